// Round 4
// baseline (12769.093 us; speedup 1.0000x reference)
//
#include <hip/hip_runtime.h>
#include <hip/hip_fp16.h>
#include <stdint.h>

// ---------- types ----------
typedef _Float16 half8 __attribute__((ext_vector_type(8)));
typedef float f32x4 __attribute__((ext_vector_type(4)));

#define GLD_LDS16(gp, lp)                                                     \
  __builtin_amdgcn_global_load_lds(                                           \
      (const __attribute__((address_space(1))) void*)(gp),                    \
      (__attribute__((address_space(3))) void*)(lp), 16, 0, 0)

// ---------- x convert: fp32 (harness upcast) -> fp16 ----------
__global__ void xcvt_kernel(const float* __restrict__ in, __half* __restrict__ out) {
  const size_t i = ((size_t)blockIdx.x * 256 + threadIdx.x) * 4;
  float4 v = *(const float4*)(in + i);
  __half2* o = (__half2*)(out + i);
  o[0] = __floats2half2_rn(v.x, v.y);
  o[1] = __floats2half2_rn(v.z, v.w);
}

// ---------- repack: qweight [K][N/8] col-packed -> [K/8][N] k-packed ----------
// Output dword for (q, n): nibble of k=8q+t placed at bits 4*(t>>1) + 16*(t&1),
// so that (p >> 4j) & 0x000F000F gives halves (k=2j, k=2j+1).
__global__ void repack_kernel(const int* __restrict__ qw, uint32_t* __restrict__ rp, int P) {
  const int N = P * 8;
  const int n = blockIdx.x * 256 + threadIdx.x;   // exact coverage
  const int j8 = n >> 3;
  const int sh = (n & 7) * 4;
  #pragma unroll
  for (int qi = 0; qi < 4; ++qi) {
    const int q = blockIdx.y * 4 + qi;
    const int* src = qw + (size_t)(q * 8) * P + j8;
    uint32_t r = 0;
    #pragma unroll
    for (int t = 0; t < 8; ++t) {
      uint32_t w = ((uint32_t)src[t * P] >> sh) & 15u;
      r |= w << (4 * (t >> 1) + 16 * (t & 1));
    }
    rp[(size_t)q * N + n] = r;
  }
}

// ---------- smz: per (group, col) pack (s_bits, (1024+z)_bits) ----------
__global__ void smz_kernel(const float* __restrict__ sc, const int* __restrict__ qz,
                           uint32_t* __restrict__ smz, int P) {
  const int N = P * 8;
  const int n = blockIdx.x * 256 + threadIdx.x;
  const int g = blockIdx.y;
  uint32_t sbits = __half_as_ushort(__float2half(sc[(size_t)g * N + n]));  // exact
  uint32_t z = ((uint32_t)qz[(size_t)g * P + (n >> 3)] >> ((n & 7) * 4)) & 15u;
  uint32_t hz = 0x6400u | z;  // fp16(1024+z), exact
  smz[(size_t)g * N + n] = sbits | (hz << 16);
}

// ---------- dequant 8 nibbles -> half8 fragment ----------
union U32H2 { uint32_t u; __half2 h; };
__device__ inline uint32_t dq_pair(uint32_t t, uint32_t s2, uint32_t z2) {
  U32H2 a, s, z, r;
  a.u = t; s.u = s2; z.u = z2;
  r.h = __hmul2(__hsub2(a.h, z.h), s.h);   // ((1024+w)-(1024+z))*s, exact sub + 1 rounding
  return r.u;
}
__device__ inline half8 dequant8(uint32_t p, uint32_t s2, uint32_t z2) {
  union { uint32_t u[4]; half8 v; } r;
  r.u[0] = dq_pair((p & 0x000F000Fu) | 0x64006400u, s2, z2);
  r.u[1] = dq_pair(((p >> 4) & 0x000F000Fu) | 0x64006400u, s2, z2);
  r.u[2] = dq_pair(((p >> 8) & 0x000F000Fu) | 0x64006400u, s2, z2);
  r.u[3] = dq_pair(((p >> 12) & 0x000F000Fu) | 0x64006400u, s2, z2);
  return r.v;
}

// ---------- fused AWQ GEMM ----------
// Block: 128 rows x NT*128 cols. 4 waves, each 128x32 per tile.
// A staged in LDS (double buffer, XOR-swizzled via pre-swizzled global source).
// B dequantized from repacked dwords straight into register fragments.
template <int KDIM, int NW, int T1OFF, int OW, bool SILU, int NT>
__global__ __launch_bounds__(256, 4) void awq_gemm(const __half* __restrict__ A,
                                                   const uint32_t* __restrict__ RP,
                                                   const uint32_t* __restrict__ SMZ,
                                                   void* __restrict__ OUT) {
  __shared__ __align__(16) unsigned char sA[2][128 * 64 * 2];  // 2 x 16KB

  const int tid = threadIdx.x;
  const int l = tid & 63;
  const int wv = tid >> 6;
  const int l15 = l & 15;
  const int l4 = l >> 4;

  const int row0 = blockIdx.y * 128;
  const int n0 = blockIdx.x * 128;

  // staging source pointers (swizzled: LDS chunk slot c at row m holds k-chunk c ^ (m&7))
  const __half* asrc[4];
  #pragma unroll
  for (int it = 0; it < 4; ++it) {
    int m = it * 32 + (tid >> 3);
    int cs = tid & 7;
    int kc = cs ^ (m & 7);
    asrc[it] = A + (size_t)(row0 + m) * KDIM + kc * 8;
  }

  int colb[NT][2];
  #pragma unroll
  for (int tile = 0; tile < NT; ++tile)
    #pragma unroll
    for (int nf = 0; nf < 2; ++nf)
      colb[tile][nf] = n0 + wv * 32 + nf * 16 + l15 + (tile ? T1OFF : 0);

  f32x4 acc[NT][2][8];  // [tile][nf][mf]
  const f32x4 zero4 = {0.f, 0.f, 0.f, 0.f};
  #pragma unroll
  for (int t = 0; t < NT; ++t)
    #pragma unroll
    for (int nf = 0; nf < 2; ++nf)
      #pragma unroll
      for (int mf = 0; mf < 8; ++mf) acc[t][nf][mf] = zero4;

  uint32_t s2[NT][2], z2[NT][2];

  constexpr int NSTEP = KDIM / 64;

  // prologue: stage step 0 into buf 0
  #pragma unroll
  for (int it = 0; it < 4; ++it)
    GLD_LDS16(asrc[it], &sA[0][it * 4096 + tid * 16]);

  for (int t = 0; t < NSTEP; ++t) {
    const int cur = t & 1;
    __syncthreads();  // compiler emits vmcnt(0) drain before s_barrier -> stage(t) complete

    if (t + 1 < NSTEP) {
      #pragma unroll
      for (int it = 0; it < 4; ++it)
        GLD_LDS16(asrc[it] + (t + 1) * 64, &sA[cur ^ 1][it * 4096 + tid * 16]);
    }

    if ((t & 1) == 0) {  // group changes every 2 K-steps (group_size 128, BK 64)
      const int g = t >> 1;
      #pragma unroll
      for (int tile = 0; tile < NT; ++tile)
        #pragma unroll
        for (int nf = 0; nf < 2; ++nf) {
          uint32_t u = SMZ[(size_t)g * NW + colb[tile][nf]];
          uint32_t lo = u & 0xFFFFu;
          s2[tile][nf] = lo | (lo << 16);
          z2[tile][nf] = (u & 0xFFFF0000u) | (u >> 16);
        }
    }

    uint32_t bq[2][NT][2];  // [kk][tile][nf]
    #pragma unroll
    for (int kk = 0; kk < 2; ++kk)
      #pragma unroll
      for (int tile = 0; tile < NT; ++tile)
        #pragma unroll
        for (int nf = 0; nf < 2; ++nf)
          bq[kk][tile][nf] = RP[(size_t)(t * 8 + kk * 4 + l4) * NW + colb[tile][nf]];

    const unsigned char* base = sA[cur];
    #pragma unroll
    for (int kk = 0; kk < 2; ++kk) {
      half8 a[8];
      #pragma unroll
      for (int mf = 0; mf < 8; ++mf) {
        int m = mf * 16 + l15;
        int chunk = (kk * 4 + l4) ^ (l15 & 7);
        a[mf] = *(const half8*)(base + m * 128 + chunk * 16);
      }
      #pragma unroll
      for (int tile = 0; tile < NT; ++tile)
        #pragma unroll
        for (int nf = 0; nf < 2; ++nf) {
          half8 b = dequant8(bq[kk][tile][nf], s2[tile][nf], z2[tile][nf]);
          #pragma unroll
          for (int mf = 0; mf < 8; ++mf)
            acc[tile][nf][mf] =
                __builtin_amdgcn_mfma_f32_16x16x32_f16(a[mf], b, acc[tile][nf][mf], 0, 0, 0);
        }
    }
  }

  // epilogue
  if (SILU) {
    __half* O = (__half*)OUT;
    #pragma unroll
    for (int nf = 0; nf < 2; ++nf)
      #pragma unroll
      for (int mf = 0; mf < 8; ++mf)
        #pragma unroll
        for (int r = 0; r < 4; ++r) {
          int row = row0 + mf * 16 + l4 * 4 + r;
          int col = n0 + wv * 32 + nf * 16 + l15;
          float gf = __half2float(__float2half(acc[0][nf][mf][r]));  // gate_up fp16 cast
          float uf = __half2float(__float2half(acc[1][nf][mf][r]));
          float sig = 1.f / (1.f + __expf(-gf));
          float sil = __half2float(__float2half(gf * sig));          // silu fp16 cast
          O[(size_t)row * OW + col] = __float2half(sil * uf);        // intermediate fp16
        }
  } else {
    float* O = (float*)OUT;
    #pragma unroll
    for (int tile = 0; tile < NT; ++tile)
      #pragma unroll
      for (int nf = 0; nf < 2; ++nf)
        #pragma unroll
        for (int mf = 0; mf < 8; ++mf)
          #pragma unroll
          for (int r = 0; r < 4; ++r) {
            int row = row0 + mf * 16 + l4 * 4 + r;
            int col = n0 + tile * T1OFF + wv * 32 + nf * 16 + l15;
            // reference result is fp16; harness stores fp32
            O[(size_t)row * OW + col] = __half2float(__float2half(acc[tile][nf][mf][r]));
          }
  }
}

// ---------- launch ----------
// Workspace phase-aliasing (stay under the round-1-proven-safe 263,397,376 B):
//   phase 1 (through GEMM1): interm | rp_gu | smz_gu | xh   = 256,688,128 B
//   phase 2 (after GEMM1):   interm | rp_dn | smz_dn        = 191,258,624 B
// rp_dn/smz_dn alias the retired rp_gu region; repack_dn runs AFTER GEMM1
// on the same stream (in-order), so no hazard.
extern "C" void kernel_launch(void* const* d_in, const int* in_sizes, int n_in,
                              void* d_out, int out_size, void* d_ws, size_t ws_size,
                              hipStream_t stream) {
  const float* x_f32 = (const float*)d_in[0];          // harness upcasts fp16 -> fp32
  const int* qw_gu = (const int*)d_in[1];
  const int* qz_gu = (const int*)d_in[2];
  const float* sc_gu = (const float*)d_in[3];          // fp32 (upcast)
  const int* qw_dn = (const int*)d_in[4];
  const int* qz_dn = (const int*)d_in[5];
  const float* sc_dn = (const float*)d_in[6];          // fp32 (upcast)

  char* ws = (char*)d_ws;
  __half* interm   = (__half*)ws;                      // 4096*18944*2   = 155,189,248
  uint32_t* rp_gu  = (uint32_t*)(ws + 155189248ull);   // 448*37888*4    =  67,895,296
  uint32_t* smz_gu = (uint32_t*)(ws + 223084544ull);   // 28*37888*4     =   4,243,456
  __half* xh       = (__half*)(ws + 227328000ull);     // 4096*3584*2    =  29,360,128
  // phase-1 high water: 256,688,128
  uint32_t* rp_dn  = (uint32_t*)(ws + 155189248ull);   // 2368*3584*4    =  33,947,648 (aliases rp_gu)
  uint32_t* smz_dn = (uint32_t*)(ws + 189136896ull);   // 148*3584*4     =   2,121,728

  // ---- phase 1: prep + GEMM1 ----
  xcvt_kernel<<<14336, 256, 0, stream>>>(x_f32, xh);   // 14336*256*4 = 14,680,064 elems
  repack_kernel<<<dim3(148, 112), 256, 0, stream>>>(qw_gu, rp_gu, 4736);  // K/8=448
  smz_kernel<<<dim3(148, 28), 256, 0, stream>>>(sc_gu, qz_gu, smz_gu, 4736);

  // GEMM1: x @ W_gu fused with silu(gate)*up -> intermediate (fp16)
  // 2 tiles per block: gate cols [n0,n0+128), up cols [n0+18944, ...)
  awq_gemm<3584, 37888, 18944, 18944, true, 2>
      <<<dim3(148, 32), 256, 0, stream>>>(xh, rp_gu, smz_gu, (void*)interm);

  // ---- phase 2: prep + GEMM2 (aliased scratch) ----
  repack_kernel<<<dim3(14, 592), 256, 0, stream>>>(qw_dn, rp_dn, 448);    // K/8=2368
  smz_kernel<<<dim3(14, 148), 256, 0, stream>>>(sc_dn, qz_dn, smz_dn, 448);

  // GEMM2: intermediate @ W_down -> d_out (fp32, fp16-rounded)
  // single 128-col tile per block -> 28x32 = 896 blocks (3.5/CU)
  awq_gemm<18944, 3584, 0, 3584, false, 1>
      <<<dim3(28, 32), 256, 0, stream>>>(interm, rp_dn, smz_dn, d_out);
}

// Round 5
// 1691.782 us; speedup vs baseline: 7.5477x; 7.5477x over previous
//
#include <hip/hip_runtime.h>
#include <hip/hip_fp16.h>
#include <stdint.h>

// ---------- types ----------
typedef _Float16 half8 __attribute__((ext_vector_type(8)));
typedef float f32x4 __attribute__((ext_vector_type(4)));

#define GLD_LDS16(gp, lp)                                                     \
  __builtin_amdgcn_global_load_lds(                                           \
      (const __attribute__((address_space(1))) void*)(gp),                    \
      (__attribute__((address_space(3))) void*)(lp), 16, 0, 0)

// ---------- x convert: fp32 (harness upcast) -> fp16 ----------
__global__ void xcvt_kernel(const float* __restrict__ in, __half* __restrict__ out) {
  const size_t i = ((size_t)blockIdx.x * 256 + threadIdx.x) * 4;
  float4 v = *(const float4*)(in + i);
  __half2* o = (__half2*)(out + i);
  o[0] = __floats2half2_rn(v.x, v.y);
  o[1] = __floats2half2_rn(v.z, v.w);
}

// ---------- repack: qweight [K][N/8] col-packed -> [K/8][N] k-packed ----------
// Output dword for (q, n): nibble of k=8q+t placed at bits 4*(t>>1) + 16*(t&1),
// so that (p >> 4j) & 0x000F000F gives halves (k=2j, k=2j+1).
__global__ void repack_kernel(const int* __restrict__ qw, uint32_t* __restrict__ rp, int P) {
  const int N = P * 8;
  const int n = blockIdx.x * 256 + threadIdx.x;   // exact coverage
  const int j8 = n >> 3;
  const int sh = (n & 7) * 4;
  #pragma unroll
  for (int qi = 0; qi < 4; ++qi) {
    const int q = blockIdx.y * 4 + qi;
    const int* src = qw + (size_t)(q * 8) * P + j8;
    uint32_t r = 0;
    #pragma unroll
    for (int t = 0; t < 8; ++t) {
      uint32_t w = ((uint32_t)src[t * P] >> sh) & 15u;
      r |= w << (4 * (t >> 1) + 16 * (t & 1));
    }
    rp[(size_t)q * N + n] = r;
  }
}

// ---------- smz: per (group, col) pack (s_bits, (1024+z)_bits) ----------
__global__ void smz_kernel(const float* __restrict__ sc, const int* __restrict__ qz,
                           uint32_t* __restrict__ smz, int P) {
  const int N = P * 8;
  const int n = blockIdx.x * 256 + threadIdx.x;
  const int g = blockIdx.y;
  uint32_t sbits = __half_as_ushort(__float2half(sc[(size_t)g * N + n]));  // exact
  uint32_t z = ((uint32_t)qz[(size_t)g * P + (n >> 3)] >> ((n & 7) * 4)) & 15u;
  uint32_t hz = 0x6400u | z;  // fp16(1024+z), exact
  smz[(size_t)g * N + n] = sbits | (hz << 16);
}

// ---------- dequant 8 nibbles -> half8 fragment ----------
union U32H2 { uint32_t u; __half2 h; };
__device__ inline uint32_t dq_pair(uint32_t t, uint32_t s2, uint32_t z2) {
  U32H2 a, s, z, r;
  a.u = t; s.u = s2; z.u = z2;
  r.h = __hmul2(__hsub2(a.h, z.h), s.h);   // ((1024+w)-(1024+z))*s, exact sub + 1 rounding
  return r.u;
}
__device__ inline half8 dequant8(uint32_t p, uint32_t s2, uint32_t z2) {
  union { uint32_t u[4]; half8 v; } r;
  r.u[0] = dq_pair((p & 0x000F000Fu) | 0x64006400u, s2, z2);
  r.u[1] = dq_pair(((p >> 4) & 0x000F000Fu) | 0x64006400u, s2, z2);
  r.u[2] = dq_pair(((p >> 8) & 0x000F000Fu) | 0x64006400u, s2, z2);
  r.u[3] = dq_pair(((p >> 12) & 0x000F000Fu) | 0x64006400u, s2, z2);
  return r.v;
}

// ---------- fused AWQ GEMM ----------
// Block: 128 rows x NT*128 cols. 4 waves, each 128x32 per tile.
// A staged in LDS (double buffer, XOR-swizzled via pre-swizzled global source).
// B packed dwords ALSO staged in LDS (double buffer, XOR-swizzled source) so the
// dequant critical path reads LDS (~120cy) instead of global (~200-900cy).
// SMZ scale/zero prefetched one group ahead in registers.
template <int KDIM, int NW, int T1OFF, int OW, bool SILU, int NT, int BXS>
__global__ __launch_bounds__(256, 2) void awq_gemm(const __half* __restrict__ A,
                                                   const uint32_t* __restrict__ RP,
                                                   const uint32_t* __restrict__ SMZ,
                                                   void* __restrict__ OUT) {
  __shared__ __align__(16) unsigned char sA[2][128 * 64 * 2];      // 2 x 16KB
  __shared__ __align__(16) unsigned char sB[2][NT * 8 * 128 * 4];  // 2 x NT*4KB

  const int tid = threadIdx.x;
  const int l = tid & 63;
  const int wv = tid >> 6;
  const int l15 = l & 15;
  const int l4 = l >> 4;

  const int row0 = blockIdx.y * 128;
  const int n0 = blockIdx.x * BXS;

  // A staging source pointers (swizzled: LDS chunk slot c at row m holds k-chunk c ^ (m&7))
  const __half* asrc[4];
  #pragma unroll
  for (int it = 0; it < 4; ++it) {
    int m = it * 32 + (tid >> 3);
    int cs = tid & 7;
    int kc = cs ^ (m & 7);
    asrc[it] = A + (size_t)(row0 + m) * KDIM + kc * 8;
  }

  // B staging source pointers: LDS dword d of qrow-row qr holds RP col (d ^ S(qr)),
  // S(qr) = ((qr&1)<<4) | ((qr>>1)<<2)  -> b32 reads land 2 lanes/bank (free).
  const uint32_t* bsrc[NT];
  #pragma unroll
  for (int it = 0; it < NT; ++it) {
    int idx = it * 256 + tid;     // [0, NT*256)
    int tile = idx >> 8;
    int qr = (idx >> 5) & 7;
    int l32 = idx & 31;
    int S = ((qr & 1) << 4) | ((qr >> 1) << 2);
    bsrc[it] = RP + (size_t)qr * NW + n0 + tile * T1OFF + ((l32 * 4) ^ S);
  }

  int colb[NT][2];
  #pragma unroll
  for (int tile = 0; tile < NT; ++tile)
    #pragma unroll
    for (int nf = 0; nf < 2; ++nf)
      colb[tile][nf] = n0 + wv * 32 + nf * 16 + l15 + (tile ? T1OFF : 0);

  f32x4 acc[NT][2][8];  // [tile][nf][mf]
  const f32x4 zero4 = {0.f, 0.f, 0.f, 0.f};
  #pragma unroll
  for (int t = 0; t < NT; ++t)
    #pragma unroll
    for (int nf = 0; nf < 2; ++nf)
      #pragma unroll
      for (int mf = 0; mf < 8; ++mf) acc[t][nf][mf] = zero4;

  uint32_t s2[NT][2], z2[NT][2], su[NT][2];

  constexpr int NSTEP = KDIM / 64;
  constexpr int NGRP = KDIM / 128;

  // prologue: stage step 0 into buf 0; prefetch SMZ group 0
  #pragma unroll
  for (int it = 0; it < 4; ++it)
    GLD_LDS16(asrc[it], &sA[0][it * 4096 + tid * 16]);
  #pragma unroll
  for (int it = 0; it < NT; ++it)
    GLD_LDS16(bsrc[it], &sB[0][(it * 256 + tid) * 16]);
  #pragma unroll
  for (int tile = 0; tile < NT; ++tile)
    #pragma unroll
    for (int nf = 0; nf < 2; ++nf)
      su[tile][nf] = SMZ[colb[tile][nf]];

  for (int t = 0; t < NSTEP; ++t) {
    const int cur = t & 1;
    __syncthreads();  // vmcnt(0) drain before s_barrier -> stage(t) complete

    if (t + 1 < NSTEP) {
      #pragma unroll
      for (int it = 0; it < 4; ++it)
        GLD_LDS16(asrc[it] + (t + 1) * 64, &sA[cur ^ 1][it * 4096 + tid * 16]);
      #pragma unroll
      for (int it = 0; it < NT; ++it)
        GLD_LDS16(bsrc[it] + (size_t)(t + 1) * 8 * NW, &sB[cur ^ 1][(it * 256 + tid) * 16]);
    }

    if ((t & 1) == 0) {  // group changes every 2 K-steps (group_size 128, BK 64)
      #pragma unroll
      for (int tile = 0; tile < NT; ++tile)
        #pragma unroll
        for (int nf = 0; nf < 2; ++nf) {
          uint32_t u = su[tile][nf];
          uint32_t lo = u & 0xFFFFu;
          s2[tile][nf] = lo | (lo << 16);
          z2[tile][nf] = (u & 0xFFFF0000u) | (u >> 16);
        }
      const int g1 = (t >> 1) + 1;
      if (g1 < NGRP) {
        #pragma unroll
        for (int tile = 0; tile < NT; ++tile)
          #pragma unroll
          for (int nf = 0; nf < 2; ++nf)
            su[tile][nf] = SMZ[(size_t)g1 * NW + colb[tile][nf]];
      }
    }

    // B dwords from LDS (swizzled address matches staging source swizzle)
    uint32_t bq[2][NT][2];  // [kk][tile][nf]
    const int bro = wv * 32 + l15;
    #pragma unroll
    for (int kk = 0; kk < 2; ++kk) {
      const int Sl = ((l4 & 1) << 4) | (kk << 3) | ((l4 >> 1) << 2);
      #pragma unroll
      for (int tile = 0; tile < NT; ++tile)
        #pragma unroll
        for (int nf = 0; nf < 2; ++nf)
          bq[kk][tile][nf] = *(const uint32_t*)&sB[cur][
              (((tile * 8 + kk * 4 + l4) * 128) + ((bro + nf * 16) ^ Sl)) * 4];
    }

    const unsigned char* base = sA[cur];
    #pragma unroll
    for (int kk = 0; kk < 2; ++kk) {
      half8 a[8];
      #pragma unroll
      for (int mf = 0; mf < 8; ++mf) {
        int m = mf * 16 + l15;
        int chunk = (kk * 4 + l4) ^ (l15 & 7);
        a[mf] = *(const half8*)(base + m * 128 + chunk * 16);
      }
      #pragma unroll
      for (int tile = 0; tile < NT; ++tile)
        #pragma unroll
        for (int nf = 0; nf < 2; ++nf) {
          half8 b = dequant8(bq[kk][tile][nf], s2[tile][nf], z2[tile][nf]);
          #pragma unroll
          for (int mf = 0; mf < 8; ++mf)
            acc[tile][nf][mf] =
                __builtin_amdgcn_mfma_f32_16x16x32_f16(a[mf], b, acc[tile][nf][mf], 0, 0, 0);
        }
    }
  }

  // epilogue
  if (SILU) {
    __half* O = (__half*)OUT;
    #pragma unroll
    for (int nf = 0; nf < 2; ++nf)
      #pragma unroll
      for (int mf = 0; mf < 8; ++mf)
        #pragma unroll
        for (int r = 0; r < 4; ++r) {
          int row = row0 + mf * 16 + l4 * 4 + r;
          int col = n0 + wv * 32 + nf * 16 + l15;
          float gf = __half2float(__float2half(acc[0][nf][mf][r]));  // gate_up fp16 cast
          float uf = __half2float(__float2half(acc[1][nf][mf][r]));
          float sig = 1.f / (1.f + __expf(-gf));
          float sil = __half2float(__float2half(gf * sig));          // silu fp16 cast
          O[(size_t)row * OW + col] = __float2half(sil * uf);        // intermediate fp16
        }
  } else {
    float* O = (float*)OUT;
    #pragma unroll
    for (int tile = 0; tile < NT; ++tile)
      #pragma unroll
      for (int nf = 0; nf < 2; ++nf)
        #pragma unroll
        for (int mf = 0; mf < 8; ++mf)
          #pragma unroll
          for (int r = 0; r < 4; ++r) {
            int row = row0 + mf * 16 + l4 * 4 + r;
            int col = n0 + tile * T1OFF + wv * 32 + nf * 16 + l15;
            // reference result is fp16; harness stores fp32
            O[(size_t)row * OW + col] = __half2float(__float2half(acc[tile][nf][mf][r]));
          }
  }
}

// ---------- launch ----------
// Workspace phase-aliasing (stay under the round-1-proven-safe 263,397,376 B):
//   phase 1 (through GEMM1): interm | rp_gu | smz_gu | xh   = 256,688,128 B
//   phase 2 (after GEMM1):   interm | rp_dn | smz_dn        = 191,258,624 B
extern "C" void kernel_launch(void* const* d_in, const int* in_sizes, int n_in,
                              void* d_out, int out_size, void* d_ws, size_t ws_size,
                              hipStream_t stream) {
  const float* x_f32 = (const float*)d_in[0];          // harness upcasts fp16 -> fp32
  const int* qw_gu = (const int*)d_in[1];
  const int* qz_gu = (const int*)d_in[2];
  const float* sc_gu = (const float*)d_in[3];          // fp32 (upcast)
  const int* qw_dn = (const int*)d_in[4];
  const int* qz_dn = (const int*)d_in[5];
  const float* sc_dn = (const float*)d_in[6];          // fp32 (upcast)

  char* ws = (char*)d_ws;
  __half* interm   = (__half*)ws;                      // 4096*18944*2   = 155,189,248
  uint32_t* rp_gu  = (uint32_t*)(ws + 155189248ull);   // 448*37888*4    =  67,895,296
  uint32_t* smz_gu = (uint32_t*)(ws + 223084544ull);   // 28*37888*4     =   4,243,456
  __half* xh       = (__half*)(ws + 227328000ull);     // 4096*3584*2    =  29,360,128
  // phase-1 high water: 256,688,128
  uint32_t* rp_dn  = (uint32_t*)(ws + 155189248ull);   // 2368*3584*4    (aliases rp_gu)
  uint32_t* smz_dn = (uint32_t*)(ws + 189136896ull);   // 148*3584*4

  // ---- phase 1: prep + GEMM1 ----
  xcvt_kernel<<<14336, 256, 0, stream>>>(x_f32, xh);
  repack_kernel<<<dim3(148, 112), 256, 0, stream>>>(qw_gu, rp_gu, 4736);  // K/8=448
  smz_kernel<<<dim3(148, 28), 256, 0, stream>>>(sc_gu, qz_gu, smz_gu, 4736);

  // GEMM1: x @ W_gu fused with silu(gate)*up -> intermediate (fp16)
  // 2 tiles per block: gate cols [n0,n0+128), up cols [n0+18944, ...)
  awq_gemm<3584, 37888, 18944, 18944, true, 2, 128>
      <<<dim3(148, 32), 256, 0, stream>>>(xh, rp_gu, smz_gu, (void*)interm);

  // ---- phase 2: prep + GEMM2 (aliased scratch) ----
  repack_kernel<<<dim3(14, 592), 256, 0, stream>>>(qw_dn, rp_dn, 448);    // K/8=2368
  smz_kernel<<<dim3(14, 148), 256, 0, stream>>>(sc_dn, qz_dn, smz_dn, 448);

  // GEMM2: intermediate @ W_down -> d_out (fp32, fp16-rounded)
  // NT=2 tiles at +0/+128, block covers 256 cols, grid (14,32)
  awq_gemm<18944, 3584, 128, 3584, false, 2, 256>
      <<<dim3(14, 32), 256, 0, stream>>>(interm, rp_dn, smz_dn, d_out);
}

// Round 7
// 1623.734 us; speedup vs baseline: 7.8640x; 1.0419x over previous
//
#include <hip/hip_runtime.h>
#include <hip/hip_fp16.h>
#include <stdint.h>

// ---------- types ----------
typedef _Float16 half8 __attribute__((ext_vector_type(8)));
typedef _Float16 h2v __attribute__((ext_vector_type(2)));
typedef float f32x4 __attribute__((ext_vector_type(4)));

#define GLD_LDS16(gp, lp)                                                     \
  __builtin_amdgcn_global_load_lds(                                           \
      (const __attribute__((address_space(1))) void*)(gp),                    \
      (__attribute__((address_space(3))) void*)(lp), 16, 0, 0)
#define GLD_LDS4(gp, lp)                                                      \
  __builtin_amdgcn_global_load_lds(                                           \
      (const __attribute__((address_space(1))) void*)(gp),                    \
      (__attribute__((address_space(3))) void*)(lp), 4, 0, 0)

// ---------- x convert: fp32 (harness upcast) -> fp16 ----------
__global__ void xcvt_kernel(const float* __restrict__ in, __half* __restrict__ out) {
  const size_t i = ((size_t)blockIdx.x * 256 + threadIdx.x) * 4;
  float4 v = *(const float4*)(in + i);
  __half2* o = (__half2*)(out + i);
  o[0] = __floats2half2_rn(v.x, v.y);
  o[1] = __floats2half2_rn(v.z, v.w);
}

// ---------- repack: qweight [K][N/8] col-packed -> [K/8][N] k-packed ----------
__global__ void repack_kernel(const int* __restrict__ qw, uint32_t* __restrict__ rp, int P) {
  const int N = P * 8;
  const int n = blockIdx.x * 256 + threadIdx.x;
  const int j8 = n >> 3;
  const int sh = (n & 7) * 4;
  #pragma unroll
  for (int qi = 0; qi < 4; ++qi) {
    const int q = blockIdx.y * 4 + qi;
    const int* src = qw + (size_t)(q * 8) * P + j8;
    uint32_t r = 0;
    #pragma unroll
    for (int t = 0; t < 8; ++t) {
      uint32_t w = ((uint32_t)src[t * P] >> sh) & 15u;
      r |= w << (4 * (t >> 1) + 16 * (t & 1));
    }
    rp[(size_t)q * N + n] = r;
  }
}

// ---------- smz: per (group, col) pack (s_bits, (1024+z)_bits) ----------
__global__ void smz_kernel(const float* __restrict__ sc, const int* __restrict__ qz,
                           uint32_t* __restrict__ smz, int P) {
  const int N = P * 8;
  const int n = blockIdx.x * 256 + threadIdx.x;
  const int g = blockIdx.y;
  uint32_t sbits = __half_as_ushort(__float2half(sc[(size_t)g * N + n]));  // exact
  uint32_t z = ((uint32_t)qz[(size_t)g * P + (n >> 3)] >> ((n & 7) * 4)) & 15u;
  uint32_t hz = 0x6400u | z;  // fp16(1024+z), exact
  smz[(size_t)g * N + n] = sbits | (hz << 16);
}

// ---------- dequant 8 nibbles -> half8 (native pk-f16 ops) ----------
union U32H2 { uint32_t u; h2v h; };
__device__ inline h2v bith2(uint32_t u) { U32H2 t; t.u = u; return t.h; }
__device__ inline half8 dequant8(uint32_t p, h2v s, h2v z) {
  U32H2 t0, t1, t2, t3;
  t0.u = (p & 0x000F000Fu) | 0x64006400u;
  t1.u = ((p >> 4) & 0x000F000Fu) | 0x64006400u;
  t2.u = ((p >> 8) & 0x000F000Fu) | 0x64006400u;
  t3.u = ((p >> 12) & 0x000F000Fu) | 0x64006400u;
  h2v v0 = (t0.h - z) * s;   // v_pk_sub_f16 (exact) + v_pk_mul_f16 (1 rounding)
  h2v v1 = (t1.h - z) * s;
  h2v v2 = (t2.h - z) * s;
  h2v v3 = (t3.h - z) * s;
  half8 r = {v0.x, v0.y, v1.x, v1.y, v2.x, v2.y, v3.x, v3.y};
  return r;
}

// ---------- fused AWQ GEMM ----------
// 128 rows x NT tiles of 128 cols per block (tile tl at n0 + tl*T1OFF,
// n0 = blockIdx.x * BXS). 4 waves, each 128x32 per tile.
// Triple-buffered staging (A tiles, B packed dwords, SMZ group table) via
// global_load_lds; ONE s_barrier per K-step preceded by a COUNTED
// s_waitcnt vmcnt(6/7) (T3/T4): two staging batches stay in flight across
// barriers -> no vmcnt(0) drain stall.
// Batch(k) = 4xA + NTxB (+1 smz when k even) VMEM ops, issued at iter k-2
// AFTER the barrier (all waves past compute(k-1), overwrite of buf k%3 safe).
// Wait-THEN-barrier ordering makes cross-wave LDS reads safe: each wave
// drains its own batch(t) before the barrier, so after the barrier the whole
// buffer (staged piecewise by all 4 waves) is visible.
template <int KDIM, int NW, int T1OFF, int OW, bool SILU, int NT, int BXS>
__global__ __launch_bounds__(256, 2) void awq_gemm(const __half* __restrict__ A,
                                                   const uint32_t* __restrict__ RP,
                                                   const uint32_t* __restrict__ SMZ,
                                                   void* __restrict__ OUT) {
  constexpr int ABUF = 128 * 64 * 2;          // 16384 B per A buffer
  constexpr int BBUF = NT * 8 * 128 * 4;      // 4096*NT per B buffer
  constexpr int BOFF = 3 * ABUF;              // 49152
  constexpr int ZOFF = BOFF + 3 * BBUF;       // smz double buffer (2 x 1024 B)
  __shared__ __align__(16) unsigned char smem[ZOFF + 2048];

  const int tid = threadIdx.x;
  const int l = tid & 63;
  const int wv = tid >> 6;
  const int l15 = l & 15;
  const int l4 = l >> 4;

  const int row0 = blockIdx.y * 128;
  const int n0 = blockIdx.x * BXS;

  // A staging sources (swizzled: LDS chunk slot c at row m holds k-chunk c ^ (m&7))
  const __half* asrc[4];
  #pragma unroll
  for (int it = 0; it < 4; ++it) {
    int m = it * 32 + (tid >> 3);
    int cs = tid & 7;
    int kc = cs ^ (m & 7);
    asrc[it] = A + (size_t)(row0 + m) * KDIM + kc * 8;
  }

  // B staging sources: LDS dword d of qrow qr holds RP col (d ^ S(qr))
  const uint32_t* bsrc[NT];
  #pragma unroll
  for (int it = 0; it < NT; ++it) {
    int idx = it * 256 + tid;
    int tile = idx >> 8;
    int qr = (idx >> 5) & 7;
    int l32 = idx & 31;
    int S = ((qr & 1) << 4) | ((qr >> 1) << 2);
    bsrc[it] = RP + (size_t)qr * NW + n0 + tile * T1OFF + ((l32 * 4) ^ S);
  }

  // SMZ staging source: thread covers (tile = tid>>7, col offset tid&127)
  const uint32_t* zsrc = SMZ + n0 + (size_t)(tid >> 7) * T1OFF + (tid & 127);

  f32x4 acc[NT][2][8];
  const f32x4 zero4 = {0.f, 0.f, 0.f, 0.f};
  #pragma unroll
  for (int t = 0; t < NT; ++t)
    #pragma unroll
    for (int nf = 0; nf < 2; ++nf)
      #pragma unroll
      for (int mf = 0; mf < 8; ++mf) acc[t][nf][mf] = zero4;

  uint32_t s2[NT][2], z2[NT][2];
  constexpr int NSTEP = KDIM / 64;

  // ---- prologue: batch(0) [A,B,smz g0] then batch(1) [A,B] ----
  #pragma unroll
  for (int it = 0; it < 4; ++it)
    GLD_LDS16(asrc[it], &smem[it * 4096 + tid * 16]);
  #pragma unroll
  for (int it = 0; it < NT; ++it)
    GLD_LDS16(bsrc[it], &smem[BOFF + (it * 256 + tid) * 16]);
  GLD_LDS4(zsrc, &smem[ZOFF + tid * 4]);
  #pragma unroll
  for (int it = 0; it < 4; ++it)
    GLD_LDS16(asrc[it] + 64, &smem[ABUF + it * 4096 + tid * 16]);
  #pragma unroll
  for (int it = 0; it < NT; ++it)
    GLD_LDS16(bsrc[it] + (size_t)8 * NW, &smem[BOFF + BBUF + (it * 256 + tid) * 16]);

  int cur = 0, stg = 2;  // buf(t%3), buf((t+2)%3)
  for (int t = 0; t < NSTEP; ++t) {
    // counted wait: drain batch(t); batch(t+1) = 6 + ((t+1)&1?0:1) stays in flight
    if (t == NSTEP - 1)      asm volatile("s_waitcnt vmcnt(0)" ::: "memory");
    else if (t & 1)          asm volatile("s_waitcnt vmcnt(7)" ::: "memory");
    else                     asm volatile("s_waitcnt vmcnt(6)" ::: "memory");
    __builtin_amdgcn_s_barrier();

    // issue batch(t+2) into buf stg
    if (t + 2 < NSTEP) {
      #pragma unroll
      for (int it = 0; it < 4; ++it)
        GLD_LDS16(asrc[it] + (size_t)(t + 2) * 64, &smem[stg * ABUF + it * 4096 + tid * 16]);
      #pragma unroll
      for (int it = 0; it < NT; ++it)
        GLD_LDS16(bsrc[it] + (size_t)(t + 2) * 8 * NW,
                  &smem[BOFF + stg * BBUF + (it * 256 + tid) * 16]);
      if (((t + 2) & 1) == 0) {  // smz for group (t+2)/2 into buf ((t+2)/2)&1
        const int g = (t + 2) >> 1;
        GLD_LDS4(zsrc + (size_t)g * NW, &smem[ZOFF + (g & 1) * 1024 + tid * 4]);
      }
    }

    if ((t & 1) == 0) {  // group boundary: unpack s/z from smz LDS buffer
      const uint32_t* zl = (const uint32_t*)&smem[ZOFF + ((t >> 1) & 1) * 1024];
      #pragma unroll
      for (int tile = 0; tile < NT; ++tile)
        #pragma unroll
        for (int nf = 0; nf < 2; ++nf) {
          uint32_t u = zl[tile * 128 + wv * 32 + nf * 16 + l15];
          uint32_t lo = u & 0xFFFFu;
          s2[tile][nf] = lo | (lo << 16);
          z2[tile][nf] = (u & 0xFFFF0000u) | (u >> 16);
        }
    }

    // B dwords from LDS (read swizzle matches staged source swizzle)
    uint32_t bq[2][NT][2];
    const int bro = wv * 32 + l15;
    const unsigned char* bbase = &smem[BOFF + cur * BBUF];
    #pragma unroll
    for (int kk = 0; kk < 2; ++kk) {
      const int Sl = ((l4 & 1) << 4) | (kk << 3) | ((l4 >> 1) << 2);
      #pragma unroll
      for (int tile = 0; tile < NT; ++tile)
        #pragma unroll
        for (int nf = 0; nf < 2; ++nf)
          bq[kk][tile][nf] = *(const uint32_t*)&bbase[
              (((tile * 8 + kk * 4 + l4) * 128) + ((bro + nf * 16) ^ Sl)) * 4];
    }

    const unsigned char* abase = &smem[cur * ABUF];
    #pragma unroll
    for (int kk = 0; kk < 2; ++kk) {
      half8 a[8];
      #pragma unroll
      for (int mf = 0; mf < 8; ++mf) {
        int m = mf * 16 + l15;
        int chunk = (kk * 4 + l4) ^ (l15 & 7);
        a[mf] = *(const half8*)(abase + m * 128 + chunk * 16);
      }
      #pragma unroll
      for (int tile = 0; tile < NT; ++tile)
        #pragma unroll
        for (int nf = 0; nf < 2; ++nf) {
          half8 b = dequant8(bq[kk][tile][nf], bith2(s2[tile][nf]), bith2(z2[tile][nf]));
          #pragma unroll
          for (int mf = 0; mf < 8; ++mf)
            acc[tile][nf][mf] =
                __builtin_amdgcn_mfma_f32_16x16x32_f16(a[mf], b, acc[tile][nf][mf], 0, 0, 0);
        }
    }

    cur = (cur == 2) ? 0 : cur + 1;
    stg = (stg == 2) ? 0 : stg + 1;
  }

  // epilogue
  if (SILU) {
    __half* O = (__half*)OUT;
    #pragma unroll
    for (int nf = 0; nf < 2; ++nf)
      #pragma unroll
      for (int mf = 0; mf < 8; ++mf)
        #pragma unroll
        for (int r = 0; r < 4; ++r) {
          int row = row0 + mf * 16 + l4 * 4 + r;
          int col = n0 + wv * 32 + nf * 16 + l15;
          float gf = __half2float(__float2half(acc[0][nf][mf][r]));  // gate_up fp16 cast
          float uf = __half2float(__float2half(acc[1][nf][mf][r]));
          float sig = 1.f / (1.f + __expf(-gf));
          float sil = __half2float(__float2half(gf * sig));          // silu fp16 cast
          O[(size_t)row * OW + col] = __float2half(sil * uf);        // intermediate fp16
        }
  } else {
    float* O = (float*)OUT;
    #pragma unroll
    for (int tile = 0; tile < NT; ++tile)
      #pragma unroll
      for (int nf = 0; nf < 2; ++nf)
        #pragma unroll
        for (int mf = 0; mf < 8; ++mf)
          #pragma unroll
          for (int r = 0; r < 4; ++r) {
            int row = row0 + mf * 16 + l4 * 4 + r;
            int col = n0 + tile * T1OFF + wv * 32 + nf * 16 + l15;
            O[(size_t)row * OW + col] = __half2float(__float2half(acc[tile][nf][mf][r]));
          }
  }
}

// ---------- launch ----------
// Workspace phase-aliasing (stay under round-1-proven-safe 263,397,376 B):
//   phase 1 (through GEMM1): interm | rp_gu | smz_gu | xh   = 256,688,128 B
//   phase 2 (after GEMM1):   interm | rp_dn | smz_dn        = 191,258,624 B
extern "C" void kernel_launch(void* const* d_in, const int* in_sizes, int n_in,
                              void* d_out, int out_size, void* d_ws, size_t ws_size,
                              hipStream_t stream) {
  const float* x_f32 = (const float*)d_in[0];          // harness upcasts fp16 -> fp32
  const int* qw_gu = (const int*)d_in[1];
  const int* qz_gu = (const int*)d_in[2];
  const float* sc_gu = (const float*)d_in[3];          // fp32 (upcast)
  const int* qw_dn = (const int*)d_in[4];
  const int* qz_dn = (const int*)d_in[5];
  const float* sc_dn = (const float*)d_in[6];          // fp32 (upcast)

  char* ws = (char*)d_ws;
  __half* interm   = (__half*)ws;                      // 155,189,248
  uint32_t* rp_gu  = (uint32_t*)(ws + 155189248ull);   // 67,895,296
  uint32_t* smz_gu = (uint32_t*)(ws + 223084544ull);   // 4,243,456
  __half* xh       = (__half*)(ws + 227328000ull);     // 29,360,128
  uint32_t* rp_dn  = (uint32_t*)(ws + 155189248ull);   // aliases rp_gu
  uint32_t* smz_dn = (uint32_t*)(ws + 189136896ull);

  // ---- phase 1: prep + GEMM1 ----
  xcvt_kernel<<<14336, 256, 0, stream>>>(x_f32, xh);
  repack_kernel<<<dim3(148, 112), 256, 0, stream>>>(qw_gu, rp_gu, 4736);
  smz_kernel<<<dim3(148, 28), 256, 0, stream>>>(sc_gu, qz_gu, smz_gu, 4736);

  // GEMM1: blocks stride 128 cols (gate at n0, up at n0+18944)
  awq_gemm<3584, 37888, 18944, 18944, true, 2, 128>
      <<<dim3(148, 32), 256, 0, stream>>>(xh, rp_gu, smz_gu, (void*)interm);

  // ---- phase 2: prep + GEMM2 (aliased scratch) ----
  repack_kernel<<<dim3(14, 592), 256, 0, stream>>>(qw_dn, rp_dn, 448);
  smz_kernel<<<dim3(14, 148), 256, 0, stream>>>(sc_dn, qz_dn, smz_dn, 448);

  // GEMM2: blocks stride 256 cols (two 128-col tiles at +0/+128)
  awq_gemm<18944, 3584, 128, 3584, false, 2, 256>
      <<<dim3(14, 32), 256, 0, stream>>>(interm, rp_dn, smz_dn, d_out);
}